// Round 13
// baseline (265.110 us; speedup 1.0000x reference)
//
#include <hip/hip_runtime.h>

#define NN 100000
#define NF 128
#define NE 1600000
#define NBK 782   // ceil(NN/128) buckets of 128 dst nodes
#define CH 4096   // edges per binning chunk
#define BINB 391  // (NE+CH-1)/CH bin blocks
#define MAXB 2816 // padded region per bucket (mean 2046, ~17 sigma headroom)
#define RED_B 512 // blocks for esum partial reduction
#define NGB 1563  // (NN+63)/64 gemm blocks
#define CVTXB 12500  // NN*NF/4/256 blocks for x-conversion
#define NPERM (NBK * 128)  // 100096 permutation slots

typedef unsigned short ushort_t;
typedef __attribute__((ext_vector_type(8))) short bf16x8;
typedef __attribute__((ext_vector_type(4))) float f32x4;

__device__ inline ushort_t f2bf(float f) {  // RNE
  union { float f; unsigned u; } v; v.f = f;
  const unsigned r = v.u + 0x7FFFu + ((v.u >> 16) & 1u);
  return (ushort_t)(r >> 16);
}
__device__ inline float bf2f(ushort_t h) {
  union { unsigned u; float f; } v; v.u = ((unsigned)h) << 16;
  return v.f;
}

// ---------------------------------------------- block-wide exclusive scan
__device__ inline void block_scan(const int* hist, int* lofs, int* wsum) {
  const int t = threadIdx.x;
  const int b4 = t * 4;
  const int h0 = hist[b4], h1 = hist[b4 + 1], h2 = hist[b4 + 2], h3 = hist[b4 + 3];
  const int tsum = h0 + h1 + h2 + h3;
  const int lane = t & 63, w = t >> 6;
  int s = tsum;
#pragma unroll
  for (int o = 1; o < 64; o <<= 1) {
    const int u = __shfl_up(s, o);
    if (lane >= o) s += u;
  }
  if (lane == 63) wsum[w] = s;
  __syncthreads();
  int add = 0;
  for (int i = 0; i < w; ++i) add += wsum[i];
  const int ex = add + s - tsum;
  lofs[b4] = ex;
  lofs[b4 + 1] = ex + h0;
  lofs[b4 + 2] = ex + h0 + h1;
  lofs[b4 + 3] = ex + h0 + h1 + h2;
}

// ---------------- merged prep: bin (blocks 0..BINB) || weight cvt || x cvt
__global__ __launch_bounds__(256) void k_prep(
    const int* __restrict__ src, const int* __restrict__ dst,
    int* __restrict__ bcursor, int* __restrict__ packed,
    const float* __restrict__ x, ushort_t* __restrict__ xb,
    const float* __restrict__ w0, const float* __restrict__ w1,
    const float* __restrict__ w2, const float* __restrict__ w3,
    ushort_t* __restrict__ wout) {
  __shared__ int hist[1024];
  __shared__ int lofs[1024];
  __shared__ int wsum[4];
  __shared__ int gofs[NBK];
  __shared__ int list[CH];
  __shared__ unsigned short blist[CH];
  const int blk = blockIdx.x;
  const int t = threadIdx.x;

  if (blk >= BINB + 64) {  // ---- x conversion (streaming)
    const int i = (blk - BINB - 64) * 256 + t;
    const float4 v = *reinterpret_cast<const float4*>(x + (size_t)i * 4);
    ushort4 o;
    o.x = f2bf(v.x); o.y = f2bf(v.y); o.z = f2bf(v.z); o.w = f2bf(v.w);
    *reinterpret_cast<ushort4*>(xb + (size_t)i * 4) = o;
    return;
  }
  if (blk >= BINB) {  // ---- weight conversion
    const int i = (blk - BINB) * 256 + t;
    wout[i] = f2bf(w0[i]);
    wout[16384 + i] = f2bf(w1[i]);
    wout[32768 + i] = f2bf(w2[i]);
    wout[49152 + i] = f2bf(w3[i]);
    return;
  }

  // ---- bin chunk
  const int e0 = blk * CH;
  const int n = min(CH, NE - e0);

  for (int i = t; i < 1024; i += 256) hist[i] = 0;
  __syncthreads();
  for (int i = t; i < n; i += 256) atomicAdd(&hist[dst[e0 + i] >> 7], 1);
  __syncthreads();
  block_scan(hist, lofs, wsum);
  __syncthreads();
  for (int b = t; b < NBK; b += 256) {
    const int cnt = hist[b];
    gofs[b] = cnt ? atomicAdd(&bcursor[b], cnt) : 0;
    hist[b] = 0;
  }
  __syncthreads();
  for (int i = t; i < n; i += 256) {
    const int d = dst[e0 + i];
    const int s = src[e0 + i];
    const int b = d >> 7;
    const int r = atomicAdd(&hist[b], 1);
    const int q = lofs[b] + r;
    list[q] = ((d & 127) << 17) | s;
    blist[q] = (unsigned short)b;
  }
  __syncthreads();
  for (int q = t; q < n; q += 256) {
    const int b = blist[q];
    const int idx = gofs[b] + (q - lofs[b]);
    if (idx < MAXB) packed[b * MAXB + idx] = list[q];
  }
}

// --------------------------------- second-level sort: exact CSR per bucket
// Also emits a degree-sorted node permutation per bucket (64-bin counting
// sort) so k_agg can pair equal-degree nodes per wave (divergence fix).
__global__ __launch_bounds__(256) void k_sort2(int* __restrict__ packed,
                                               const int* __restrict__ bcursor,
                                               int* __restrict__ offs,
                                               int* __restrict__ ends,
                                               int* __restrict__ perm) {
  __shared__ int plist[MAXB];
  __shared__ int slist[MAXB];
  __shared__ int hist[128];
  __shared__ int lofs[128];
  __shared__ int wsum2[2];
  __shared__ int dcnt[64];
  __shared__ int dofs[64];
  const int b = blockIdx.x, t = threadIdx.x;
  const int beg = b * MAXB;
  const int n = min(bcursor[b], MAXB);
  const int nvalid = min(128, NN - (b << 7));

  for (int i = t; i < n; i += 256) plist[i] = packed[beg + i];
  if (t < 128) hist[t] = 0;
  if (t < 64) dcnt[t] = 0;
  __syncthreads();
  for (int i = t; i < n; i += 256) atomicAdd(&hist[plist[i] >> 17], 1);
  __syncthreads();
  int s = (t < 128) ? hist[t] : 0;
  {
    const int lane = t & 63;
#pragma unroll
    for (int o = 1; o < 64; o <<= 1) {
      const int u = __shfl_up(s, o);
      if (lane >= o) s += u;
    }
    if (t < 128 && lane == 63) wsum2[t >> 6] = s;
  }
  __syncthreads();
  int mybin = 0;
  if (t < 128) {
    const int mydeg = hist[t];
    const int ex = s - mydeg + ((t >= 64) ? wsum2[0] : 0);
    lofs[t] = ex;
    const int node = (b << 7) + t;
    if (node < NN) {
      offs[node] = beg + ex;
      ends[node] = beg + ex + mydeg;
    }
    hist[t] = 0;
    mybin = min(mydeg, 63);
    if (t < nvalid) atomicAdd(&dcnt[mybin], 1);
  }
  __syncthreads();
  // exclusive scan of the 64 degree bins (wave 0)
  if (t < 64) {
    const int v = dcnt[t];
    int sc = v;
#pragma unroll
    for (int o = 1; o < 64; o <<= 1) {
      const int u = __shfl_up(sc, o);
      if (t >= o) sc += u;
    }
    dofs[t] = sc - v;
  }
  __syncthreads();
  if (t < 128) {
    if (t < nvalid) {
      const int pos = atomicAdd(&dofs[mybin], 1);
      perm[(b << 7) + pos] = (b << 7) + t;
    } else {
      perm[(b << 7) + t] = -1;
    }
  }
  // main edge sort (scatter by local dst, then coalesced writeback)
  for (int i = t; i < n; i += 256) {
    const int p = plist[i];
    const int ld = p >> 17;
    const int r = atomicAdd(&hist[ld], 1);
    slist[lofs[ld] + r] = p & 0x1FFFF;
  }
  __syncthreads();
  for (int i = t; i < n; i += 256) packed[beg + i] = slist[i];
}

// --------------------------------------------- gather-based aggregation (bf16)
// 2 nodes per wave via degree-sorted perm (equal-degree pairing -> no
// divergence waste). Half-wave (32 lanes) per node, ushort4 (8B)/lane.
// Unroll 8 (unroll 16 measured WORSE: VGPR/occ, r10).
__global__ __launch_bounds__(256) void k_agg(const ushort_t* __restrict__ feat,
                                             const int* __restrict__ offs,
                                             const int* __restrict__ ends,
                                             const int* __restrict__ srcs,
                                             const int* __restrict__ perm,
                                             ushort_t* __restrict__ out) {
  const int lane = threadIdx.x & 63;
  const int wid = threadIdx.x >> 6;
  const int idx = blockIdx.x * 8 + wid * 2 + (lane >> 5);
  const int node = perm[idx];
  if (node < 0) return;
  const int c = (lane & 31) * 4;
  const int beg = offs[node];
  const int end = ends[node];

  float x0 = 0.f, y0 = 0.f, z0 = 0.f, w0 = 0.f;
  float x1 = 0.f, y1 = 0.f, z1 = 0.f, w1 = 0.f;
  float x2 = 0.f, y2 = 0.f, z2 = 0.f, w2 = 0.f;
  float x3 = 0.f, y3 = 0.f, z3 = 0.f, w3 = 0.f;
  float x4 = 0.f, y4 = 0.f, z4 = 0.f, w4 = 0.f;
  float x5 = 0.f, y5 = 0.f, z5 = 0.f, w5 = 0.f;
  float x6 = 0.f, y6 = 0.f, z6 = 0.f, w6 = 0.f;
  float x7 = 0.f, y7 = 0.f, z7 = 0.f, w7 = 0.f;

  int e = beg;
  for (; e + 8 <= end; e += 8) {
    const int s0 = srcs[e], s1 = srcs[e + 1], s2 = srcs[e + 2], s3 = srcs[e + 3];
    const int s4 = srcs[e + 4], s5 = srcs[e + 5], s6 = srcs[e + 6], s7 = srcs[e + 7];
    const ushort4 u0 = *(const ushort4*)(feat + s0 * NF + c);
    const ushort4 u1 = *(const ushort4*)(feat + s1 * NF + c);
    const ushort4 u2 = *(const ushort4*)(feat + s2 * NF + c);
    const ushort4 u3 = *(const ushort4*)(feat + s3 * NF + c);
    const ushort4 u4 = *(const ushort4*)(feat + s4 * NF + c);
    const ushort4 u5 = *(const ushort4*)(feat + s5 * NF + c);
    const ushort4 u6 = *(const ushort4*)(feat + s6 * NF + c);
    const ushort4 u7 = *(const ushort4*)(feat + s7 * NF + c);
    x0 += bf2f(u0.x); y0 += bf2f(u0.y); z0 += bf2f(u0.z); w0 += bf2f(u0.w);
    x1 += bf2f(u1.x); y1 += bf2f(u1.y); z1 += bf2f(u1.z); w1 += bf2f(u1.w);
    x2 += bf2f(u2.x); y2 += bf2f(u2.y); z2 += bf2f(u2.z); w2 += bf2f(u2.w);
    x3 += bf2f(u3.x); y3 += bf2f(u3.y); z3 += bf2f(u3.z); w3 += bf2f(u3.w);
    x4 += bf2f(u4.x); y4 += bf2f(u4.y); z4 += bf2f(u4.z); w4 += bf2f(u4.w);
    x5 += bf2f(u5.x); y5 += bf2f(u5.y); z5 += bf2f(u5.z); w5 += bf2f(u5.w);
    x6 += bf2f(u6.x); y6 += bf2f(u6.y); z6 += bf2f(u6.z); w6 += bf2f(u6.w);
    x7 += bf2f(u7.x); y7 += bf2f(u7.y); z7 += bf2f(u7.z); w7 += bf2f(u7.w);
  }
  for (; e + 2 <= end; e += 2) {
    const int s0 = srcs[e], s1 = srcs[e + 1];
    const ushort4 u0 = *(const ushort4*)(feat + s0 * NF + c);
    const ushort4 u1 = *(const ushort4*)(feat + s1 * NF + c);
    x0 += bf2f(u0.x); y0 += bf2f(u0.y); z0 += bf2f(u0.z); w0 += bf2f(u0.w);
    x1 += bf2f(u1.x); y1 += bf2f(u1.y); z1 += bf2f(u1.z); w1 += bf2f(u1.w);
  }
  for (; e < end; ++e) {
    const int s = srcs[e];
    const ushort4 u = *(const ushort4*)(feat + s * NF + c);
    x0 += bf2f(u.x); y0 += bf2f(u.y); z0 += bf2f(u.z); w0 += bf2f(u.w);
  }
  ushort4 r;
  r.x = f2bf(((x0 + x1) + (x2 + x3)) + ((x4 + x5) + (x6 + x7)));
  r.y = f2bf(((y0 + y1) + (y2 + y3)) + ((y4 + y5) + (y6 + y7)));
  r.z = f2bf(((z0 + z1) + (z2 + z3)) + ((z4 + z5) + (z6 + z7)));
  r.w = f2bf(((w0 + w1) + (w2 + w3)) + ((w4 + w5) + (w6 + w7)));
  *(ushort4*)(out + node * NF + c) = r;
}

// ------------------------------------------------------------- MFMA GEMM
// MODE 0: write relu(v) as bf16 to out (layer 1).
// MODE 1: layer 2+3 fused epilogue via shfl_xor j-reduction:
//         y1[node] = h2.W3rel, P2[block] = sum_nodes h2.W3root.
template <int MODE>
__global__ __launch_bounds__(256) void k_gemm(const ushort_t* __restrict__ A1,
                                              const ushort_t* __restrict__ A2,
                                              const ushort_t* __restrict__ B1,
                                              const ushort_t* __restrict__ B2,
                                              const float* __restrict__ bias,
                                              ushort_t* __restrict__ out,
                                              const float* __restrict__ W3rel,
                                              const float* __restrict__ W3root,
                                              float* __restrict__ y1,
                                              float* __restrict__ P2) {
  __shared__ ushort_t As[64][264];  // +8 pad: 2-way LDS conflict only
  __shared__ float y1s[4][64];
  __shared__ float y2s[4][64];
  const int tid = threadIdx.x;
  const int lane = tid & 63;
  const int wid = tid >> 6;
  const int bm = blockIdx.x * 64;

  const int jb = wid * 32 + (lane & 15);
  const int kc = (lane >> 4) * 8;
  bf16x8 bfrag[2][8];
#pragma unroll
  for (int nt = 0; nt < 2; ++nt) {
    const int j = jb + nt * 16;
#pragma unroll
    for (int ks = 0; ks < 4; ++ks) {
      bfrag[nt][ks] = *reinterpret_cast<const bf16x8*>(B1 + j * 128 + ks * 32 + kc);
      bfrag[nt][ks + 4] = *reinterpret_cast<const bf16x8*>(B2 + j * 128 + ks * 32 + kc);
    }
  }

  {
    const int r = tid >> 2, p = tid & 3;
    const int node = bm + r;
#pragma unroll
    for (int s = 0; s < 2; ++s) {
      const ushort_t* __restrict__ sp = s ? A2 : A1;
#pragma unroll
      for (int q = 0; q < 4; ++q) {
        const int col = p * 32 + q * 8;
        bf16x8 v = (node < NN) ? *reinterpret_cast<const bf16x8*>(sp + node * 128 + col)
                               : (bf16x8)(short)0;
        *reinterpret_cast<bf16x8*>(&As[r][s * 128 + col]) = v;
      }
    }
  }
  __syncthreads();

  f32x4 acc[4][2];
#pragma unroll
  for (int mt = 0; mt < 4; ++mt) {
    acc[mt][0] = (f32x4)0.f;
    acc[mt][1] = (f32x4)0.f;
  }

  const int ar = lane & 15;
#pragma unroll
  for (int ks = 0; ks < 8; ++ks) {
#pragma unroll
    for (int mt = 0; mt < 4; ++mt) {
      const bf16x8 a = *reinterpret_cast<const bf16x8*>(&As[mt * 16 + ar][ks * 32 + kc]);
      acc[mt][0] = __builtin_amdgcn_mfma_f32_16x16x32_bf16(a, bfrag[0][ks], acc[mt][0], 0, 0, 0);
      acc[mt][1] = __builtin_amdgcn_mfma_f32_16x16x32_bf16(a, bfrag[1][ks], acc[mt][1], 0, 0, 0);
    }
  }

  // epilogue (C/D: col=lane&15 -> j, row=(lane>>4)*4+reg -> node)
  const int rg = (lane >> 4) * 4;
  if (MODE == 0) {
#pragma unroll
    for (int nt = 0; nt < 2; ++nt) {
      const int j = jb + nt * 16;
      const float bv = bias[j];
#pragma unroll
      for (int mt = 0; mt < 4; ++mt) {
#pragma unroll
        for (int r = 0; r < 4; ++r) {
          const int node = bm + mt * 16 + rg + r;
          if (node < NN) {
            const float v = fmaxf(acc[mt][nt][r] + bv, 0.f);
            out[node * 128 + j] = f2bf(v);
          }
        }
      }
    }
  } else {
    const float bv0 = bias[jb], bv1 = bias[jb + 16];
    const float wr0 = W3rel[jb], wr1 = W3rel[jb + 16];
    const float wt0 = W3root[jb], wt1 = W3root[jb + 16];
#pragma unroll
    for (int mt = 0; mt < 4; ++mt) {
#pragma unroll
      for (int r = 0; r < 4; ++r) {
        const float v0 = fmaxf(acc[mt][0][r] + bv0, 0.f);
        const float v1 = fmaxf(acc[mt][1][r] + bv1, 0.f);
        float s1 = v0 * wr0 + v1 * wr1;
        float s2 = v0 * wt0 + v1 * wt1;
#pragma unroll
        for (int o = 1; o < 16; o <<= 1) {
          s1 += __shfl_xor(s1, o);
          s2 += __shfl_xor(s2, o);
        }
        if ((lane & 15) == 0) {
          const int nloc = mt * 16 + rg + r;
          y1s[wid][nloc] = s1;
          y2s[wid][nloc] = s2;
        }
      }
    }
    __syncthreads();
    if (tid < 64) {
      const int node = bm + tid;
      const float s1 = (y1s[0][tid] + y1s[1][tid]) + (y1s[2][tid] + y1s[3][tid]);
      float p = (node < NN)
                    ? (y2s[0][tid] + y2s[1][tid]) + (y2s[2][tid] + y2s[3][tid])
                    : 0.f;
      if (node < NN) y1[node] = s1;
#pragma unroll
      for (int o = 32; o > 0; o >>= 1) p += __shfl_down(p, o);
      if (tid == 0) P2[blockIdx.x] = p;
    }
  }
}

// --------------------------- P1 partials: Σ_e y1[src_e] (L2-resident table)
__global__ __launch_bounds__(256) void k_esum(const int* __restrict__ src,
                                              const float* __restrict__ y1,
                                              float* __restrict__ P1) {
  float p = 0.f;
  const int stride = RED_B * 256;
  for (int e = blockIdx.x * 256 + threadIdx.x; e < NE; e += stride)
    p += y1[src[e]];
#pragma unroll
  for (int o = 32; o > 0; o >>= 1) p += __shfl_down(p, o);
  __shared__ float tmp[4];
  const int lane = threadIdx.x & 63, w = threadIdx.x >> 6;
  if (lane == 0) tmp[w] = p;
  __syncthreads();
  if (threadIdx.x == 0)
    P1[blockIdx.x] = (tmp[0] + tmp[1]) + (tmp[2] + tmp[3]);
}

__global__ __launch_bounds__(256) void k_final(const float* __restrict__ P1,
                                               const float* __restrict__ P2,
                                               const float* __restrict__ b3,
                                               float* __restrict__ out) {
  const int t = threadIdx.x;
  float v = P1[t] + P1[t + 256];
  for (int i = t; i < NGB; i += 256) v += P2[i];
#pragma unroll
  for (int o = 32; o > 0; o >>= 1) v += __shfl_down(v, o);
  __shared__ float tmp[4];
  if ((t & 63) == 0) tmp[t >> 6] = v;
  __syncthreads();
  if (t == 0)
    out[0] = ((tmp[0] + tmp[1]) + (tmp[2] + tmp[3])) * (1.0f / NN) + b3[0];
}

// ---------------------------------------------------------------------------
extern "C" void kernel_launch(void* const* d_in, const int* in_sizes, int n_in,
                              void* d_out, int out_size, void* d_ws, size_t ws_size,
                              hipStream_t stream) {
  const float* x = (const float*)d_in[0];
  const int* ei = (const int*)d_in[1];
  const float* W1rel = (const float*)d_in[2];
  const float* b1 = (const float*)d_in[3];
  const float* W1root = (const float*)d_in[4];
  const float* W2rel = (const float*)d_in[5];
  const float* b2 = (const float*)d_in[6];
  const float* W2root = (const float*)d_in[7];
  const float* W3rel = (const float*)d_in[8];
  const float* b3 = (const float*)d_in[9];
  const float* W3root = (const float*)d_in[10];

  const int* src = ei;       // edge_index[0]
  const int* dst = ei + NE;  // edge_index[1]

  char* ws = (char*)d_ws;
  size_t off = 0;
  ushort_t* xb   = (ushort_t*)(ws + off); off += (size_t)NN * NF * 2;  // 25.6 MB
  ushort_t* h1b  = (ushort_t*)(ws + off); off += (size_t)NN * NF * 2;  // 25.6 MB
  ushort_t* aggb = (ushort_t*)(ws + off); off += (size_t)NN * NF * 2;  // 25.6 MB
  ushort_t* Wb   = (ushort_t*)(ws + off); off += 65536 * 2;            // 128 KB
  int* offs    = (int*)(ws + off); off += (size_t)NN * 4;              // 400 KB
  int* ends    = (int*)(ws + off); off += (size_t)NN * 4;              // 400 KB
  float* y1    = (float*)(ws + off); off += (size_t)NN * 4;            // 400 KB
  int* perm    = (int*)(ws + off); off += (size_t)NPERM * 4;           // 400 KB
  int* bcursor = (int*)(ws + off); off += 1024 * 4;
  float* P1    = (float*)(ws + off); off += RED_B * 4;
  float* P2    = (float*)(ws + off); off += 2048 * 4;
  int* packed  = (int*)(ws + off); off += (size_t)NBK * MAXB * 4;      // 8.8 MB
  int* srcs    = packed;  // k_sort2 rewrites packed in place
  float* outp = (float*)d_out;

  hipMemsetAsync(bcursor, 0, 1024 * sizeof(int), stream);

  // merged prep: bin || weight-cvt || x-cvt (concurrent in one dispatch)
  k_prep<<<BINB + 64 + CVTXB, 256, 0, stream>>>(src, dst, bcursor, packed,
                                                x, xb, W1rel, W1root, W2rel,
                                                W2root, Wb);
  k_sort2<<<NBK, 256, 0, stream>>>(packed, bcursor, offs, ends, perm);

  // layer 1
  k_agg<<<NPERM / 8, 256, 0, stream>>>(xb, offs, ends, srcs, perm, aggb);
  k_gemm<0><<<NGB, 256, 0, stream>>>(aggb, xb, Wb, Wb + 16384, b1, h1b,
                                     nullptr, nullptr, nullptr, nullptr);

  // layer 2 + 3 epilogue fusion (h2 never stored)
  k_agg<<<NPERM / 8, 256, 0, stream>>>(h1b, offs, ends, srcs, perm, aggb);
  k_gemm<1><<<NGB, 256, 0, stream>>>(aggb, h1b, Wb + 32768, Wb + 49152, b2, nullptr,
                                     W3rel, W3root, y1, P2);

  // final: Σ_e y1[src_e] + Σ P2 -> scalar
  k_esum<<<RED_B, 256, 0, stream>>>(src, y1, P1);
  k_final<<<1, 256, 0, stream>>>(P1, P2, b3, outp);
}

// Round 14
// 244.143 us; speedup vs baseline: 1.0859x; 1.0859x over previous
//
#include <hip/hip_runtime.h>

#define NN 100000
#define NF 128
#define NE 1600000
#define NBK 782   // ceil(NN/128) buckets of 128 dst nodes
#define CH 4096   // edges per binning chunk (CH=2048 measured neutral-worse, r11)
#define BINB 391  // (NE+CH-1)/CH bin blocks
#define MAXB 2816 // padded region per bucket (mean 2046, ~17 sigma headroom)
#define RED_B 512 // blocks for esum partial reduction
#define NGB 1563  // (NN+63)/64 gemm blocks
#define CVTXB 12500  // NN*NF/4/256 blocks for x-conversion

typedef unsigned short ushort_t;
typedef __attribute__((ext_vector_type(8))) short bf16x8;
typedef __attribute__((ext_vector_type(4))) float f32x4;

__device__ inline ushort_t f2bf(float f) {  // RNE
  union { float f; unsigned u; } v; v.f = f;
  const unsigned r = v.u + 0x7FFFu + ((v.u >> 16) & 1u);
  return (ushort_t)(r >> 16);
}
__device__ inline float bf2f(ushort_t h) {
  union { unsigned u; float f; } v; v.u = ((unsigned)h) << 16;
  return v.f;
}

// ---------------------------------------------- block-wide exclusive scan
__device__ inline void block_scan(const int* hist, int* lofs, int* wsum) {
  const int t = threadIdx.x;
  const int b4 = t * 4;
  const int h0 = hist[b4], h1 = hist[b4 + 1], h2 = hist[b4 + 2], h3 = hist[b4 + 3];
  const int tsum = h0 + h1 + h2 + h3;
  const int lane = t & 63, w = t >> 6;
  int s = tsum;
#pragma unroll
  for (int o = 1; o < 64; o <<= 1) {
    const int u = __shfl_up(s, o);
    if (lane >= o) s += u;
  }
  if (lane == 63) wsum[w] = s;
  __syncthreads();
  int add = 0;
  for (int i = 0; i < w; ++i) add += wsum[i];
  const int ex = add + s - tsum;
  lofs[b4] = ex;
  lofs[b4 + 1] = ex + h0;
  lofs[b4 + 2] = ex + h0 + h1;
  lofs[b4 + 3] = ex + h0 + h1 + h2;
}

// ---------------- merged prep: bin (blocks 0..BINB) || weight cvt || x cvt
// Independent workloads co-scheduled in one dispatch: bin is LDS/atomic-bound,
// cvt is BW-bound -> they overlap instead of serializing on the stream.
__global__ __launch_bounds__(256) void k_prep(
    const int* __restrict__ src, const int* __restrict__ dst,
    int* __restrict__ bcursor, int* __restrict__ packed,
    const float* __restrict__ x, ushort_t* __restrict__ xb,
    const float* __restrict__ w0, const float* __restrict__ w1,
    const float* __restrict__ w2, const float* __restrict__ w3,
    ushort_t* __restrict__ wout) {
  __shared__ int hist[1024];
  __shared__ int lofs[1024];
  __shared__ int wsum[4];
  __shared__ int gofs[NBK];
  __shared__ int list[CH];
  __shared__ unsigned short blist[CH];
  const int blk = blockIdx.x;
  const int t = threadIdx.x;

  if (blk >= BINB + 64) {  // ---- x conversion (streaming)
    const int i = (blk - BINB - 64) * 256 + t;
    const float4 v = *reinterpret_cast<const float4*>(x + (size_t)i * 4);
    ushort4 o;
    o.x = f2bf(v.x); o.y = f2bf(v.y); o.z = f2bf(v.z); o.w = f2bf(v.w);
    *reinterpret_cast<ushort4*>(xb + (size_t)i * 4) = o;
    return;
  }
  if (blk >= BINB) {  // ---- weight conversion
    const int i = (blk - BINB) * 256 + t;
    wout[i] = f2bf(w0[i]);
    wout[16384 + i] = f2bf(w1[i]);
    wout[32768 + i] = f2bf(w2[i]);
    wout[49152 + i] = f2bf(w3[i]);
    return;
  }

  // ---- bin chunk
  const int e0 = blk * CH;
  const int n = min(CH, NE - e0);

  for (int i = t; i < 1024; i += 256) hist[i] = 0;
  __syncthreads();
  for (int i = t; i < n; i += 256) atomicAdd(&hist[dst[e0 + i] >> 7], 1);
  __syncthreads();
  block_scan(hist, lofs, wsum);
  __syncthreads();
  for (int b = t; b < NBK; b += 256) {
    const int cnt = hist[b];
    gofs[b] = cnt ? atomicAdd(&bcursor[b], cnt) : 0;
    hist[b] = 0;
  }
  __syncthreads();
  for (int i = t; i < n; i += 256) {
    const int d = dst[e0 + i];
    const int s = src[e0 + i];
    const int b = d >> 7;
    const int r = atomicAdd(&hist[b], 1);
    const int q = lofs[b] + r;
    list[q] = ((d & 127) << 17) | s;
    blist[q] = (unsigned short)b;
  }
  __syncthreads();
  for (int q = t; q < n; q += 256) {
    const int b = blist[q];
    const int idx = gofs[b] + (q - lofs[b]);
    if (idx < MAXB) packed[b * MAXB + idx] = list[q];
  }
}

// --------------------------------- second-level sort: exact CSR per bucket
__global__ __launch_bounds__(256) void k_sort2(int* __restrict__ packed,
                                               const int* __restrict__ bcursor,
                                               int* __restrict__ offs,
                                               int* __restrict__ ends) {
  __shared__ int plist[MAXB];
  __shared__ int slist[MAXB];
  __shared__ int hist[128];
  __shared__ int lofs[128];
  __shared__ int wsum2[2];
  const int b = blockIdx.x, t = threadIdx.x;
  const int beg = b * MAXB;
  const int n = min(bcursor[b], MAXB);

  for (int i = t; i < n; i += 256) plist[i] = packed[beg + i];
  if (t < 128) hist[t] = 0;
  __syncthreads();
  for (int i = t; i < n; i += 256) atomicAdd(&hist[plist[i] >> 17], 1);
  __syncthreads();
  int s = (t < 128) ? hist[t] : 0;
  {
    const int lane = t & 63;
#pragma unroll
    for (int o = 1; o < 64; o <<= 1) {
      const int u = __shfl_up(s, o);
      if (lane >= o) s += u;
    }
    if (t < 128 && lane == 63) wsum2[t >> 6] = s;
  }
  __syncthreads();
  if (t < 128) {
    const int ex = s - hist[t] + ((t >= 64) ? wsum2[0] : 0);
    lofs[t] = ex;
    const int node = (b << 7) + t;
    if (node < NN) {
      offs[node] = beg + ex;
      ends[node] = beg + ex + hist[t];
    }
    hist[t] = 0;
  }
  __syncthreads();
  for (int i = t; i < n; i += 256) {
    const int p = plist[i];
    const int ld = p >> 17;
    const int r = atomicAdd(&hist[ld], 1);
    slist[lofs[ld] + r] = p & 0x1FFFF;
  }
  __syncthreads();
  for (int i = t; i < n; i += 256) packed[beg + i] = slist[i];
}

// --------------------------------------------- gather-based aggregation (bf16)
// 2 nodes per wave: half-wave (32 lanes) per node, ushort4 (8B)/lane =
// 256B row per half. Unroll 8. Measured plateau ~61us: unroll-16 (r10),
// degree-sorted pairing (r13) both WORSE; this is the random-gather
// operating point of L2/L3 (~105 G lines/s).
__global__ __launch_bounds__(256) void k_agg(const ushort_t* __restrict__ feat,
                                             const int* __restrict__ offs,
                                             const int* __restrict__ ends,
                                             const int* __restrict__ srcs,
                                             ushort_t* __restrict__ out) {
  const int lane = threadIdx.x & 63;
  const int wid = threadIdx.x >> 6;
  const int node = blockIdx.x * 8 + wid * 2 + (lane >> 5);
  if (node >= NN) return;
  const int c = (lane & 31) * 4;
  const int beg = offs[node];
  const int end = ends[node];

  float x0 = 0.f, y0 = 0.f, z0 = 0.f, w0 = 0.f;
  float x1 = 0.f, y1 = 0.f, z1 = 0.f, w1 = 0.f;
  float x2 = 0.f, y2 = 0.f, z2 = 0.f, w2 = 0.f;
  float x3 = 0.f, y3 = 0.f, z3 = 0.f, w3 = 0.f;
  float x4 = 0.f, y4 = 0.f, z4 = 0.f, w4 = 0.f;
  float x5 = 0.f, y5 = 0.f, z5 = 0.f, w5 = 0.f;
  float x6 = 0.f, y6 = 0.f, z6 = 0.f, w6 = 0.f;
  float x7 = 0.f, y7 = 0.f, z7 = 0.f, w7 = 0.f;

  int e = beg;
  for (; e + 8 <= end; e += 8) {
    const int s0 = srcs[e], s1 = srcs[e + 1], s2 = srcs[e + 2], s3 = srcs[e + 3];
    const int s4 = srcs[e + 4], s5 = srcs[e + 5], s6 = srcs[e + 6], s7 = srcs[e + 7];
    const ushort4 u0 = *(const ushort4*)(feat + s0 * NF + c);
    const ushort4 u1 = *(const ushort4*)(feat + s1 * NF + c);
    const ushort4 u2 = *(const ushort4*)(feat + s2 * NF + c);
    const ushort4 u3 = *(const ushort4*)(feat + s3 * NF + c);
    const ushort4 u4 = *(const ushort4*)(feat + s4 * NF + c);
    const ushort4 u5 = *(const ushort4*)(feat + s5 * NF + c);
    const ushort4 u6 = *(const ushort4*)(feat + s6 * NF + c);
    const ushort4 u7 = *(const ushort4*)(feat + s7 * NF + c);
    x0 += bf2f(u0.x); y0 += bf2f(u0.y); z0 += bf2f(u0.z); w0 += bf2f(u0.w);
    x1 += bf2f(u1.x); y1 += bf2f(u1.y); z1 += bf2f(u1.z); w1 += bf2f(u1.w);
    x2 += bf2f(u2.x); y2 += bf2f(u2.y); z2 += bf2f(u2.z); w2 += bf2f(u2.w);
    x3 += bf2f(u3.x); y3 += bf2f(u3.y); z3 += bf2f(u3.z); w3 += bf2f(u3.w);
    x4 += bf2f(u4.x); y4 += bf2f(u4.y); z4 += bf2f(u4.z); w4 += bf2f(u4.w);
    x5 += bf2f(u5.x); y5 += bf2f(u5.y); z5 += bf2f(u5.z); w5 += bf2f(u5.w);
    x6 += bf2f(u6.x); y6 += bf2f(u6.y); z6 += bf2f(u6.z); w6 += bf2f(u6.w);
    x7 += bf2f(u7.x); y7 += bf2f(u7.y); z7 += bf2f(u7.z); w7 += bf2f(u7.w);
  }
  for (; e + 2 <= end; e += 2) {
    const int s0 = srcs[e], s1 = srcs[e + 1];
    const ushort4 u0 = *(const ushort4*)(feat + s0 * NF + c);
    const ushort4 u1 = *(const ushort4*)(feat + s1 * NF + c);
    x0 += bf2f(u0.x); y0 += bf2f(u0.y); z0 += bf2f(u0.z); w0 += bf2f(u0.w);
    x1 += bf2f(u1.x); y1 += bf2f(u1.y); z1 += bf2f(u1.z); w1 += bf2f(u1.w);
  }
  for (; e < end; ++e) {
    const int s = srcs[e];
    const ushort4 u = *(const ushort4*)(feat + s * NF + c);
    x0 += bf2f(u.x); y0 += bf2f(u.y); z0 += bf2f(u.z); w0 += bf2f(u.w);
  }
  ushort4 r;
  r.x = f2bf(((x0 + x1) + (x2 + x3)) + ((x4 + x5) + (x6 + x7)));
  r.y = f2bf(((y0 + y1) + (y2 + y3)) + ((y4 + y5) + (y6 + y7)));
  r.z = f2bf(((z0 + z1) + (z2 + z3)) + ((z4 + z5) + (z6 + z7)));
  r.w = f2bf(((w0 + w1) + (w2 + w3)) + ((w4 + w5) + (w6 + w7)));
  *(ushort4*)(out + node * NF + c) = r;
}

// ------------------------------------------------------------- MFMA GEMM
// MODE 0: write relu(v) as bf16 to out (layer 1).
// MODE 1: layer 2+3 fused epilogue via shfl_xor j-reduction:
//         y1[node] = h2.W3rel, P2[block] = sum_nodes h2.W3root.
template <int MODE>
__global__ __launch_bounds__(256) void k_gemm(const ushort_t* __restrict__ A1,
                                              const ushort_t* __restrict__ A2,
                                              const ushort_t* __restrict__ B1,
                                              const ushort_t* __restrict__ B2,
                                              const float* __restrict__ bias,
                                              ushort_t* __restrict__ out,
                                              const float* __restrict__ W3rel,
                                              const float* __restrict__ W3root,
                                              float* __restrict__ y1,
                                              float* __restrict__ P2) {
  __shared__ ushort_t As[64][264];  // +8 pad: 2-way LDS conflict only
  __shared__ float y1s[4][64];
  __shared__ float y2s[4][64];
  const int tid = threadIdx.x;
  const int lane = tid & 63;
  const int wid = tid >> 6;
  const int bm = blockIdx.x * 64;

  const int jb = wid * 32 + (lane & 15);
  const int kc = (lane >> 4) * 8;
  bf16x8 bfrag[2][8];
#pragma unroll
  for (int nt = 0; nt < 2; ++nt) {
    const int j = jb + nt * 16;
#pragma unroll
    for (int ks = 0; ks < 4; ++ks) {
      bfrag[nt][ks] = *reinterpret_cast<const bf16x8*>(B1 + j * 128 + ks * 32 + kc);
      bfrag[nt][ks + 4] = *reinterpret_cast<const bf16x8*>(B2 + j * 128 + ks * 32 + kc);
    }
  }

  {
    const int r = tid >> 2, p = tid & 3;
    const int node = bm + r;
#pragma unroll
    for (int s = 0; s < 2; ++s) {
      const ushort_t* __restrict__ sp = s ? A2 : A1;
#pragma unroll
      for (int q = 0; q < 4; ++q) {
        const int col = p * 32 + q * 8;
        bf16x8 v = (node < NN) ? *reinterpret_cast<const bf16x8*>(sp + node * 128 + col)
                               : (bf16x8)(short)0;
        *reinterpret_cast<bf16x8*>(&As[r][s * 128 + col]) = v;
      }
    }
  }
  __syncthreads();

  f32x4 acc[4][2];
#pragma unroll
  for (int mt = 0; mt < 4; ++mt) {
    acc[mt][0] = (f32x4)0.f;
    acc[mt][1] = (f32x4)0.f;
  }

  const int ar = lane & 15;
#pragma unroll
  for (int ks = 0; ks < 8; ++ks) {
#pragma unroll
    for (int mt = 0; mt < 4; ++mt) {
      const bf16x8 a = *reinterpret_cast<const bf16x8*>(&As[mt * 16 + ar][ks * 32 + kc]);
      acc[mt][0] = __builtin_amdgcn_mfma_f32_16x16x32_bf16(a, bfrag[0][ks], acc[mt][0], 0, 0, 0);
      acc[mt][1] = __builtin_amdgcn_mfma_f32_16x16x32_bf16(a, bfrag[1][ks], acc[mt][1], 0, 0, 0);
    }
  }

  // epilogue (C/D: col=lane&15 -> j, row=(lane>>4)*4+reg -> node)
  const int rg = (lane >> 4) * 4;
  if (MODE == 0) {
#pragma unroll
    for (int nt = 0; nt < 2; ++nt) {
      const int j = jb + nt * 16;
      const float bv = bias[j];
#pragma unroll
      for (int mt = 0; mt < 4; ++mt) {
#pragma unroll
        for (int r = 0; r < 4; ++r) {
          const int node = bm + mt * 16 + rg + r;
          if (node < NN) {
            const float v = fmaxf(acc[mt][nt][r] + bv, 0.f);
            out[node * 128 + j] = f2bf(v);
          }
        }
      }
    }
  } else {
    const float bv0 = bias[jb], bv1 = bias[jb + 16];
    const float wr0 = W3rel[jb], wr1 = W3rel[jb + 16];
    const float wt0 = W3root[jb], wt1 = W3root[jb + 16];
#pragma unroll
    for (int mt = 0; mt < 4; ++mt) {
#pragma unroll
      for (int r = 0; r < 4; ++r) {
        const float v0 = fmaxf(acc[mt][0][r] + bv0, 0.f);
        const float v1 = fmaxf(acc[mt][1][r] + bv1, 0.f);
        float s1 = v0 * wr0 + v1 * wr1;
        float s2 = v0 * wt0 + v1 * wt1;
#pragma unroll
        for (int o = 1; o < 16; o <<= 1) {
          s1 += __shfl_xor(s1, o);
          s2 += __shfl_xor(s2, o);
        }
        if ((lane & 15) == 0) {
          const int nloc = mt * 16 + rg + r;
          y1s[wid][nloc] = s1;
          y2s[wid][nloc] = s2;
        }
      }
    }
    __syncthreads();
    if (tid < 64) {
      const int node = bm + tid;
      const float s1 = (y1s[0][tid] + y1s[1][tid]) + (y1s[2][tid] + y1s[3][tid]);
      float p = (node < NN)
                    ? (y2s[0][tid] + y2s[1][tid]) + (y2s[2][tid] + y2s[3][tid])
                    : 0.f;
      if (node < NN) y1[node] = s1;
#pragma unroll
      for (int o = 32; o > 0; o >>= 1) p += __shfl_down(p, o);
      if (tid == 0) P2[blockIdx.x] = p;
    }
  }
}

// --------------------------- P1 partials: Σ_e y1[src_e] (L2-resident table)
__global__ __launch_bounds__(256) void k_esum(const int* __restrict__ src,
                                              const float* __restrict__ y1,
                                              float* __restrict__ P1) {
  float p = 0.f;
  const int stride = RED_B * 256;
  for (int e = blockIdx.x * 256 + threadIdx.x; e < NE; e += stride)
    p += y1[src[e]];
#pragma unroll
  for (int o = 32; o > 0; o >>= 1) p += __shfl_down(p, o);
  __shared__ float tmp[4];
  const int lane = threadIdx.x & 63, w = threadIdx.x >> 6;
  if (lane == 0) tmp[w] = p;
  __syncthreads();
  if (threadIdx.x == 0)
    P1[blockIdx.x] = (tmp[0] + tmp[1]) + (tmp[2] + tmp[3]);
}

__global__ __launch_bounds__(256) void k_final(const float* __restrict__ P1,
                                               const float* __restrict__ P2,
                                               const float* __restrict__ b3,
                                               float* __restrict__ out) {
  const int t = threadIdx.x;
  float v = P1[t] + P1[t + 256];
  for (int i = t; i < NGB; i += 256) v += P2[i];
#pragma unroll
  for (int o = 32; o > 0; o >>= 1) v += __shfl_down(v, o);
  __shared__ float tmp[4];
  if ((t & 63) == 0) tmp[t >> 6] = v;
  __syncthreads();
  if (t == 0)
    out[0] = ((tmp[0] + tmp[1]) + (tmp[2] + tmp[3])) * (1.0f / NN) + b3[0];
}

// ---------------------------------------------------------------------------
extern "C" void kernel_launch(void* const* d_in, const int* in_sizes, int n_in,
                              void* d_out, int out_size, void* d_ws, size_t ws_size,
                              hipStream_t stream) {
  const float* x = (const float*)d_in[0];
  const int* ei = (const int*)d_in[1];
  const float* W1rel = (const float*)d_in[2];
  const float* b1 = (const float*)d_in[3];
  const float* W1root = (const float*)d_in[4];
  const float* W2rel = (const float*)d_in[5];
  const float* b2 = (const float*)d_in[6];
  const float* W2root = (const float*)d_in[7];
  const float* W3rel = (const float*)d_in[8];
  const float* b3 = (const float*)d_in[9];
  const float* W3root = (const float*)d_in[10];

  const int* src = ei;       // edge_index[0]
  const int* dst = ei + NE;  // edge_index[1]

  char* ws = (char*)d_ws;
  size_t off = 0;
  ushort_t* xb   = (ushort_t*)(ws + off); off += (size_t)NN * NF * 2;  // 25.6 MB
  ushort_t* h1b  = (ushort_t*)(ws + off); off += (size_t)NN * NF * 2;  // 25.6 MB
  ushort_t* aggb = (ushort_t*)(ws + off); off += (size_t)NN * NF * 2;  // 25.6 MB
  ushort_t* Wb   = (ushort_t*)(ws + off); off += 65536 * 2;            // 128 KB
  int* offs    = (int*)(ws + off); off += (size_t)NN * 4;              // 400 KB
  int* ends    = (int*)(ws + off); off += (size_t)NN * 4;              // 400 KB
  float* y1    = (float*)(ws + off); off += (size_t)NN * 4;            // 400 KB
  int* bcursor = (int*)(ws + off); off += 1024 * 4;
  float* P1    = (float*)(ws + off); off += RED_B * 4;
  float* P2    = (float*)(ws + off); off += 2048 * 4;
  int* packed  = (int*)(ws + off); off += (size_t)NBK * MAXB * 4;      // 8.8 MB
  int* srcs    = packed;  // k_sort2 rewrites packed in place
  float* outp = (float*)d_out;

  hipMemsetAsync(bcursor, 0, 1024 * sizeof(int), stream);

  // merged prep: bin || weight-cvt || x-cvt (concurrent in one dispatch)
  k_prep<<<BINB + 64 + CVTXB, 256, 0, stream>>>(src, dst, bcursor, packed,
                                                x, xb, W1rel, W1root, W2rel,
                                                W2root, Wb);
  k_sort2<<<NBK, 256, 0, stream>>>(packed, bcursor, offs, ends);

  // layer 1
  k_agg<<<(NN + 7) / 8, 256, 0, stream>>>(xb, offs, ends, srcs, aggb);
  k_gemm<0><<<NGB, 256, 0, stream>>>(aggb, xb, Wb, Wb + 16384, b1, h1b,
                                     nullptr, nullptr, nullptr, nullptr);

  // layer 2 + 3 epilogue fusion (h2 never stored)
  k_agg<<<(NN + 7) / 8, 256, 0, stream>>>(h1b, offs, ends, srcs, aggb);
  k_gemm<1><<<NGB, 256, 0, stream>>>(aggb, h1b, Wb + 32768, Wb + 49152, b2, nullptr,
                                     W3rel, W3root, y1, P2);

  // final: Σ_e y1[src_e] + Σ P2 -> scalar
  k_esum<<<RED_B, 256, 0, stream>>>(src, y1, P1);
  k_final<<<1, 256, 0, stream>>>(P1, P2, b3, outp);
}

// Round 15
// 201.293 us; speedup vs baseline: 1.3170x; 1.2129x over previous
//
#include <hip/hip_runtime.h>

#define NN 100000
#define NF 128
#define NE 1600000
#define NBK 782   // ceil(NN/128) buckets of 128 dst nodes
#define CH 4096   // edges per binning chunk
#define BINB 391  // (NE+CH-1)/CH bin blocks
#define MAXB 2816 // padded region per bucket (mean 2046, ~17 sigma headroom)
#define RED_B 512 // blocks for esum partial reduction
#define NGB 1563  // (NN+63)/64 gemm blocks
#define CVTXB 12500  // NN*NF/4/256 blocks for x-conversion

typedef unsigned short ushort_t;
typedef unsigned char uchar_t;
typedef __attribute__((ext_vector_type(8))) short bf16x8;
typedef __attribute__((ext_vector_type(4))) float f32x4;
typedef __attribute__((ext_vector_type(2))) float f32x2;

__device__ inline ushort_t f2bf(float f) {  // RNE
  union { float f; unsigned u; } v; v.f = f;
  const unsigned r = v.u + 0x7FFFu + ((v.u >> 16) & 1u);
  return (ushort_t)(r >> 16);
}
__device__ inline float bf2f(ushort_t h) {
  union { unsigned u; float f; } v; v.u = ((unsigned)h) << 16;
  return v.f;
}

// ---------------------------------------------- block-wide exclusive scan
__device__ inline void block_scan(const int* hist, int* lofs, int* wsum) {
  const int t = threadIdx.x;
  const int b4 = t * 4;
  const int h0 = hist[b4], h1 = hist[b4 + 1], h2 = hist[b4 + 2], h3 = hist[b4 + 3];
  const int tsum = h0 + h1 + h2 + h3;
  const int lane = t & 63, w = t >> 6;
  int s = tsum;
#pragma unroll
  for (int o = 1; o < 64; o <<= 1) {
    const int u = __shfl_up(s, o);
    if (lane >= o) s += u;
  }
  if (lane == 63) wsum[w] = s;
  __syncthreads();
  int add = 0;
  for (int i = 0; i < w; ++i) add += wsum[i];
  const int ex = add + s - tsum;
  lofs[b4] = ex;
  lofs[b4 + 1] = ex + h0;
  lofs[b4 + 2] = ex + h0 + h1;
  lofs[b4 + 3] = ex + h0 + h1 + h2;
}

// ---------------- merged prep: bin (blocks 0..BINB) || weight cvt || x cvt
// x-cvt emits BOTH bf16 (GEMM root operand) and fp8 e4m3 (gather table).
__global__ __launch_bounds__(256) void k_prep(
    const int* __restrict__ src, const int* __restrict__ dst,
    int* __restrict__ bcursor, int* __restrict__ packed,
    const float* __restrict__ x, ushort_t* __restrict__ xb,
    unsigned* __restrict__ x8,
    const float* __restrict__ w0, const float* __restrict__ w1,
    const float* __restrict__ w2, const float* __restrict__ w3,
    ushort_t* __restrict__ wout) {
  __shared__ int hist[1024];
  __shared__ int lofs[1024];
  __shared__ int wsum[4];
  __shared__ int gofs[NBK];
  __shared__ int list[CH];
  __shared__ unsigned short blist[CH];
  const int blk = blockIdx.x;
  const int t = threadIdx.x;

  if (blk >= BINB + 64) {  // ---- x conversion (streaming)
    const int i = (blk - BINB - 64) * 256 + t;
    const float4 v = *reinterpret_cast<const float4*>(x + (size_t)i * 4);
    ushort4 o;
    o.x = f2bf(v.x); o.y = f2bf(v.y); o.z = f2bf(v.z); o.w = f2bf(v.w);
    *reinterpret_cast<ushort4*>(xb + (size_t)i * 4) = o;
    int u8 = __builtin_amdgcn_cvt_pk_fp8_f32(v.x, v.y, 0, false);
    u8 = __builtin_amdgcn_cvt_pk_fp8_f32(v.z, v.w, u8, true);
    x8[i] = (unsigned)u8;
    return;
  }
  if (blk >= BINB) {  // ---- weight conversion
    const int i = (blk - BINB) * 256 + t;
    wout[i] = f2bf(w0[i]);
    wout[16384 + i] = f2bf(w1[i]);
    wout[32768 + i] = f2bf(w2[i]);
    wout[49152 + i] = f2bf(w3[i]);
    return;
  }

  // ---- bin chunk
  const int e0 = blk * CH;
  const int n = min(CH, NE - e0);

  for (int i = t; i < 1024; i += 256) hist[i] = 0;
  __syncthreads();
  for (int i = t; i < n; i += 256) atomicAdd(&hist[dst[e0 + i] >> 7], 1);
  __syncthreads();
  block_scan(hist, lofs, wsum);
  __syncthreads();
  for (int b = t; b < NBK; b += 256) {
    const int cnt = hist[b];
    gofs[b] = cnt ? atomicAdd(&bcursor[b], cnt) : 0;
    hist[b] = 0;
  }
  __syncthreads();
  for (int i = t; i < n; i += 256) {
    const int d = dst[e0 + i];
    const int s = src[e0 + i];
    const int b = d >> 7;
    const int r = atomicAdd(&hist[b], 1);
    const int q = lofs[b] + r;
    list[q] = ((d & 127) << 17) | s;
    blist[q] = (unsigned short)b;
  }
  __syncthreads();
  for (int q = t; q < n; q += 256) {
    const int b = blist[q];
    const int idx = gofs[b] + (q - lofs[b]);
    if (idx < MAXB) packed[b * MAXB + idx] = list[q];
  }
}

// --------------------------------- second-level sort: exact CSR per bucket
__global__ __launch_bounds__(256) void k_sort2(int* __restrict__ packed,
                                               const int* __restrict__ bcursor,
                                               int* __restrict__ offs,
                                               int* __restrict__ ends) {
  __shared__ int plist[MAXB];
  __shared__ int slist[MAXB];
  __shared__ int hist[128];
  __shared__ int lofs[128];
  __shared__ int wsum2[2];
  const int b = blockIdx.x, t = threadIdx.x;
  const int beg = b * MAXB;
  const int n = min(bcursor[b], MAXB);

  for (int i = t; i < n; i += 256) plist[i] = packed[beg + i];
  if (t < 128) hist[t] = 0;
  __syncthreads();
  for (int i = t; i < n; i += 256) atomicAdd(&hist[plist[i] >> 17], 1);
  __syncthreads();
  int s = (t < 128) ? hist[t] : 0;
  {
    const int lane = t & 63;
#pragma unroll
    for (int o = 1; o < 64; o <<= 1) {
      const int u = __shfl_up(s, o);
      if (lane >= o) s += u;
    }
    if (t < 128 && lane == 63) wsum2[t >> 6] = s;
  }
  __syncthreads();
  if (t < 128) {
    const int ex = s - hist[t] + ((t >= 64) ? wsum2[0] : 0);
    lofs[t] = ex;
    const int node = (b << 7) + t;
    if (node < NN) {
      offs[node] = beg + ex;
      ends[node] = beg + ex + hist[t];
    }
    hist[t] = 0;
  }
  __syncthreads();
  for (int i = t; i < n; i += 256) {
    const int p = plist[i];
    const int ld = p >> 17;
    const int r = atomicAdd(&hist[ld], 1);
    slist[lofs[ld] + r] = p & 0x1FFFF;
  }
  __syncthreads();
  for (int i = t; i < n; i += 256) packed[beg + i] = slist[i];
}

// ------------------------------------- gather-based aggregation (fp8 table)
// k_agg is line-request-bound (~105 G lines/s: warm-L3 replays take the same
// time as cold). fp8 rows = 128B = 2 lines/edge (vs 4 at bf16) -> halve time.
// 2 nodes per wave: half-wave (32 lanes) per node, uint (4 fp8 feats)/lane.
// Accumulate fp32, output bf16 (GEMM operand precision unchanged).
__global__ __launch_bounds__(256) void k_agg8(const uchar_t* __restrict__ f8,
                                              const int* __restrict__ offs,
                                              const int* __restrict__ ends,
                                              const int* __restrict__ srcs,
                                              ushort_t* __restrict__ out) {
  const int lane = threadIdx.x & 63;
  const int wid = threadIdx.x >> 6;
  const int node = blockIdx.x * 8 + wid * 2 + (lane >> 5);
  if (node >= NN) return;
  const int c = (lane & 31) * 4;  // feature index (4 feats = 4 bytes per lane)
  const int beg = offs[node];
  const int end = ends[node];

  float x0 = 0.f, y0 = 0.f, z0 = 0.f, w0 = 0.f;
  float x1 = 0.f, y1 = 0.f, z1 = 0.f, w1 = 0.f;
  float x2 = 0.f, y2 = 0.f, z2 = 0.f, w2 = 0.f;
  float x3 = 0.f, y3 = 0.f, z3 = 0.f, w3 = 0.f;
  float x4 = 0.f, y4 = 0.f, z4 = 0.f, w4 = 0.f;
  float x5 = 0.f, y5 = 0.f, z5 = 0.f, w5 = 0.f;
  float x6 = 0.f, y6 = 0.f, z6 = 0.f, w6 = 0.f;
  float x7 = 0.f, y7 = 0.f, z7 = 0.f, w7 = 0.f;

  int e = beg;
  for (; e + 8 <= end; e += 8) {
    const int s0 = srcs[e], s1 = srcs[e + 1], s2 = srcs[e + 2], s3 = srcs[e + 3];
    const int s4 = srcs[e + 4], s5 = srcs[e + 5], s6 = srcs[e + 6], s7 = srcs[e + 7];
    const unsigned u0 = *(const unsigned*)(f8 + s0 * NF + c);
    const unsigned u1 = *(const unsigned*)(f8 + s1 * NF + c);
    const unsigned u2 = *(const unsigned*)(f8 + s2 * NF + c);
    const unsigned u3 = *(const unsigned*)(f8 + s3 * NF + c);
    const unsigned u4 = *(const unsigned*)(f8 + s4 * NF + c);
    const unsigned u5 = *(const unsigned*)(f8 + s5 * NF + c);
    const unsigned u6 = *(const unsigned*)(f8 + s6 * NF + c);
    const unsigned u7 = *(const unsigned*)(f8 + s7 * NF + c);
    {
      const f32x2 a = __builtin_amdgcn_cvt_pk_f32_fp8((int)u0, false);
      const f32x2 b = __builtin_amdgcn_cvt_pk_f32_fp8((int)u0, true);
      x0 += a[0]; y0 += a[1]; z0 += b[0]; w0 += b[1];
    }
    {
      const f32x2 a = __builtin_amdgcn_cvt_pk_f32_fp8((int)u1, false);
      const f32x2 b = __builtin_amdgcn_cvt_pk_f32_fp8((int)u1, true);
      x1 += a[0]; y1 += a[1]; z1 += b[0]; w1 += b[1];
    }
    {
      const f32x2 a = __builtin_amdgcn_cvt_pk_f32_fp8((int)u2, false);
      const f32x2 b = __builtin_amdgcn_cvt_pk_f32_fp8((int)u2, true);
      x2 += a[0]; y2 += a[1]; z2 += b[0]; w2 += b[1];
    }
    {
      const f32x2 a = __builtin_amdgcn_cvt_pk_f32_fp8((int)u3, false);
      const f32x2 b = __builtin_amdgcn_cvt_pk_f32_fp8((int)u3, true);
      x3 += a[0]; y3 += a[1]; z3 += b[0]; w3 += b[1];
    }
    {
      const f32x2 a = __builtin_amdgcn_cvt_pk_f32_fp8((int)u4, false);
      const f32x2 b = __builtin_amdgcn_cvt_pk_f32_fp8((int)u4, true);
      x4 += a[0]; y4 += a[1]; z4 += b[0]; w4 += b[1];
    }
    {
      const f32x2 a = __builtin_amdgcn_cvt_pk_f32_fp8((int)u5, false);
      const f32x2 b = __builtin_amdgcn_cvt_pk_f32_fp8((int)u5, true);
      x5 += a[0]; y5 += a[1]; z5 += b[0]; w5 += b[1];
    }
    {
      const f32x2 a = __builtin_amdgcn_cvt_pk_f32_fp8((int)u6, false);
      const f32x2 b = __builtin_amdgcn_cvt_pk_f32_fp8((int)u6, true);
      x6 += a[0]; y6 += a[1]; z6 += b[0]; w6 += b[1];
    }
    {
      const f32x2 a = __builtin_amdgcn_cvt_pk_f32_fp8((int)u7, false);
      const f32x2 b = __builtin_amdgcn_cvt_pk_f32_fp8((int)u7, true);
      x7 += a[0]; y7 += a[1]; z7 += b[0]; w7 += b[1];
    }
  }
  for (; e + 2 <= end; e += 2) {
    const int s0 = srcs[e], s1 = srcs[e + 1];
    const unsigned u0 = *(const unsigned*)(f8 + s0 * NF + c);
    const unsigned u1 = *(const unsigned*)(f8 + s1 * NF + c);
    {
      const f32x2 a = __builtin_amdgcn_cvt_pk_f32_fp8((int)u0, false);
      const f32x2 b = __builtin_amdgcn_cvt_pk_f32_fp8((int)u0, true);
      x0 += a[0]; y0 += a[1]; z0 += b[0]; w0 += b[1];
    }
    {
      const f32x2 a = __builtin_amdgcn_cvt_pk_f32_fp8((int)u1, false);
      const f32x2 b = __builtin_amdgcn_cvt_pk_f32_fp8((int)u1, true);
      x1 += a[0]; y1 += a[1]; z1 += b[0]; w1 += b[1];
    }
  }
  for (; e < end; ++e) {
    const unsigned u = *(const unsigned*)(f8 + srcs[e] * NF + c);
    const f32x2 a = __builtin_amdgcn_cvt_pk_f32_fp8((int)u, false);
    const f32x2 b = __builtin_amdgcn_cvt_pk_f32_fp8((int)u, true);
    x0 += a[0]; y0 += a[1]; z0 += b[0]; w0 += b[1];
  }
  ushort4 r;
  r.x = f2bf(((x0 + x1) + (x2 + x3)) + ((x4 + x5) + (x6 + x7)));
  r.y = f2bf(((y0 + y1) + (y2 + y3)) + ((y4 + y5) + (y6 + y7)));
  r.z = f2bf(((z0 + z1) + (z2 + z3)) + ((z4 + z5) + (z6 + z7)));
  r.w = f2bf(((w0 + w1) + (w2 + w3)) + ((w4 + w5) + (w6 + w7)));
  *(ushort4*)(out + node * NF + c) = r;
}

// ------------------------------------------------------------- MFMA GEMM
// MODE 0: write relu(v) as bf16 to out AND fp8 to out8 (layer-2 gather table).
// MODE 1: layer 2+3 fused epilogue via shfl_xor j-reduction:
//         y1[node] = h2.W3rel, P2[block] = sum_nodes h2.W3root.
template <int MODE>
__global__ __launch_bounds__(256) void k_gemm(const ushort_t* __restrict__ A1,
                                              const ushort_t* __restrict__ A2,
                                              const ushort_t* __restrict__ B1,
                                              const ushort_t* __restrict__ B2,
                                              const float* __restrict__ bias,
                                              ushort_t* __restrict__ out,
                                              uchar_t* __restrict__ out8,
                                              const float* __restrict__ W3rel,
                                              const float* __restrict__ W3root,
                                              float* __restrict__ y1,
                                              float* __restrict__ P2) {
  __shared__ ushort_t As[64][264];  // +8 pad: 2-way LDS conflict only
  __shared__ float y1s[4][64];
  __shared__ float y2s[4][64];
  const int tid = threadIdx.x;
  const int lane = tid & 63;
  const int wid = tid >> 6;
  const int bm = blockIdx.x * 64;

  const int jb = wid * 32 + (lane & 15);
  const int kc = (lane >> 4) * 8;
  bf16x8 bfrag[2][8];
#pragma unroll
  for (int nt = 0; nt < 2; ++nt) {
    const int j = jb + nt * 16;
#pragma unroll
    for (int ks = 0; ks < 4; ++ks) {
      bfrag[nt][ks] = *reinterpret_cast<const bf16x8*>(B1 + j * 128 + ks * 32 + kc);
      bfrag[nt][ks + 4] = *reinterpret_cast<const bf16x8*>(B2 + j * 128 + ks * 32 + kc);
    }
  }

  {
    const int r = tid >> 2, p = tid & 3;
    const int node = bm + r;
#pragma unroll
    for (int s = 0; s < 2; ++s) {
      const ushort_t* __restrict__ sp = s ? A2 : A1;
#pragma unroll
      for (int q = 0; q < 4; ++q) {
        const int col = p * 32 + q * 8;
        bf16x8 v = (node < NN) ? *reinterpret_cast<const bf16x8*>(sp + node * 128 + col)
                               : (bf16x8)(short)0;
        *reinterpret_cast<bf16x8*>(&As[r][s * 128 + col]) = v;
      }
    }
  }
  __syncthreads();

  f32x4 acc[4][2];
#pragma unroll
  for (int mt = 0; mt < 4; ++mt) {
    acc[mt][0] = (f32x4)0.f;
    acc[mt][1] = (f32x4)0.f;
  }

  const int ar = lane & 15;
#pragma unroll
  for (int ks = 0; ks < 8; ++ks) {
#pragma unroll
    for (int mt = 0; mt < 4; ++mt) {
      const bf16x8 a = *reinterpret_cast<const bf16x8*>(&As[mt * 16 + ar][ks * 32 + kc]);
      acc[mt][0] = __builtin_amdgcn_mfma_f32_16x16x32_bf16(a, bfrag[0][ks], acc[mt][0], 0, 0, 0);
      acc[mt][1] = __builtin_amdgcn_mfma_f32_16x16x32_bf16(a, bfrag[1][ks], acc[mt][1], 0, 0, 0);
    }
  }

  // epilogue (C/D: col=lane&15 -> j, row=(lane>>4)*4+reg -> node)
  const int rg = (lane >> 4) * 4;
  if (MODE == 0) {
#pragma unroll
    for (int nt = 0; nt < 2; ++nt) {
      const int j = jb + nt * 16;
      const float bv = bias[j];
#pragma unroll
      for (int mt = 0; mt < 4; ++mt) {
#pragma unroll
        for (int r = 0; r < 4; ++r) {
          const int node = bm + mt * 16 + rg + r;
          if (node < NN) {
            const float v = fmaxf(acc[mt][nt][r] + bv, 0.f);
            out[node * 128 + j] = f2bf(v);
            const int u8 = __builtin_amdgcn_cvt_pk_fp8_f32(v, v, 0, false);
            out8[node * 128 + j] = (uchar_t)(u8 & 0xFF);
          }
        }
      }
    }
  } else {
    const float bv0 = bias[jb], bv1 = bias[jb + 16];
    const float wr0 = W3rel[jb], wr1 = W3rel[jb + 16];
    const float wt0 = W3root[jb], wt1 = W3root[jb + 16];
#pragma unroll
    for (int mt = 0; mt < 4; ++mt) {
#pragma unroll
      for (int r = 0; r < 4; ++r) {
        const float v0 = fmaxf(acc[mt][0][r] + bv0, 0.f);
        const float v1 = fmaxf(acc[mt][1][r] + bv1, 0.f);
        float s1 = v0 * wr0 + v1 * wr1;
        float s2 = v0 * wt0 + v1 * wt1;
#pragma unroll
        for (int o = 1; o < 16; o <<= 1) {
          s1 += __shfl_xor(s1, o);
          s2 += __shfl_xor(s2, o);
        }
        if ((lane & 15) == 0) {
          const int nloc = mt * 16 + rg + r;
          y1s[wid][nloc] = s1;
          y2s[wid][nloc] = s2;
        }
      }
    }
    __syncthreads();
    if (tid < 64) {
      const int node = bm + tid;
      const float s1 = (y1s[0][tid] + y1s[1][tid]) + (y1s[2][tid] + y1s[3][tid]);
      float p = (node < NN)
                    ? (y2s[0][tid] + y2s[1][tid]) + (y2s[2][tid] + y2s[3][tid])
                    : 0.f;
      if (node < NN) y1[node] = s1;
#pragma unroll
      for (int o = 32; o > 0; o >>= 1) p += __shfl_down(p, o);
      if (tid == 0) P2[blockIdx.x] = p;
    }
  }
}

// --------------------------- P1 partials: Σ_e y1[src_e] (L2-resident table)
__global__ __launch_bounds__(256) void k_esum(const int* __restrict__ src,
                                              const float* __restrict__ y1,
                                              float* __restrict__ P1) {
  float p = 0.f;
  const int stride = RED_B * 256;
  for (int e = blockIdx.x * 256 + threadIdx.x; e < NE; e += stride)
    p += y1[src[e]];
#pragma unroll
  for (int o = 32; o > 0; o >>= 1) p += __shfl_down(p, o);
  __shared__ float tmp[4];
  const int lane = threadIdx.x & 63, w = threadIdx.x >> 6;
  if (lane == 0) tmp[w] = p;
  __syncthreads();
  if (threadIdx.x == 0)
    P1[blockIdx.x] = (tmp[0] + tmp[1]) + (tmp[2] + tmp[3]);
}

__global__ __launch_bounds__(256) void k_final(const float* __restrict__ P1,
                                               const float* __restrict__ P2,
                                               const float* __restrict__ b3,
                                               float* __restrict__ out) {
  const int t = threadIdx.x;
  float v = P1[t] + P1[t + 256];
  for (int i = t; i < NGB; i += 256) v += P2[i];
#pragma unroll
  for (int o = 32; o > 0; o >>= 1) v += __shfl_down(v, o);
  __shared__ float tmp[4];
  if ((t & 63) == 0) tmp[t >> 6] = v;
  __syncthreads();
  if (t == 0)
    out[0] = ((tmp[0] + tmp[1]) + (tmp[2] + tmp[3])) * (1.0f / NN) + b3[0];
}

// ---------------------------------------------------------------------------
extern "C" void kernel_launch(void* const* d_in, const int* in_sizes, int n_in,
                              void* d_out, int out_size, void* d_ws, size_t ws_size,
                              hipStream_t stream) {
  const float* x = (const float*)d_in[0];
  const int* ei = (const int*)d_in[1];
  const float* W1rel = (const float*)d_in[2];
  const float* b1 = (const float*)d_in[3];
  const float* W1root = (const float*)d_in[4];
  const float* W2rel = (const float*)d_in[5];
  const float* b2 = (const float*)d_in[6];
  const float* W2root = (const float*)d_in[7];
  const float* W3rel = (const float*)d_in[8];
  const float* b3 = (const float*)d_in[9];
  const float* W3root = (const float*)d_in[10];

  const int* src = ei;       // edge_index[0]
  const int* dst = ei + NE;  // edge_index[1]

  char* ws = (char*)d_ws;
  size_t off = 0;
  ushort_t* xb   = (ushort_t*)(ws + off); off += (size_t)NN * NF * 2;  // 25.6 MB
  ushort_t* h1b  = (ushort_t*)(ws + off); off += (size_t)NN * NF * 2;  // 25.6 MB
  ushort_t* aggb = (ushort_t*)(ws + off); off += (size_t)NN * NF * 2;  // 25.6 MB
  uchar_t* x8    = (uchar_t*)(ws + off);  off += (size_t)NN * NF;      // 12.8 MB
  ushort_t* Wb   = (ushort_t*)(ws + off); off += 65536 * 2;            // 128 KB
  int* offs    = (int*)(ws + off); off += (size_t)NN * 4;              // 400 KB
  int* ends    = (int*)(ws + off); off += (size_t)NN * 4;              // 400 KB
  float* y1    = (float*)(ws + off); off += (size_t)NN * 4;            // 400 KB
  int* bcursor = (int*)(ws + off); off += 1024 * 4;
  float* P1    = (float*)(ws + off); off += RED_B * 4;
  float* P2    = (float*)(ws + off); off += 2048 * 4;
  int* packed  = (int*)(ws + off); off += (size_t)NBK * MAXB * 4;      // 8.8 MB
  int* srcs    = packed;     // k_sort2 rewrites packed in place
  uchar_t* h1f8 = x8;        // x8 dead after layer-1 agg -> alias h1 fp8 table
  float* outp = (float*)d_out;

  hipMemsetAsync(bcursor, 0, 1024 * sizeof(int), stream);

  // merged prep: bin || weight-cvt || x-cvt(bf16+fp8) (concurrent)
  k_prep<<<BINB + 64 + CVTXB, 256, 0, stream>>>(src, dst, bcursor, packed,
                                                x, xb, (unsigned*)x8,
                                                W1rel, W1root, W2rel, W2root, Wb);
  k_sort2<<<NBK, 256, 0, stream>>>(packed, bcursor, offs, ends);

  // layer 1: fp8 gather -> bf16 agg; MFMA; h1 written bf16 + fp8
  k_agg8<<<(NN + 7) / 8, 256, 0, stream>>>(x8, offs, ends, srcs, aggb);
  k_gemm<0><<<NGB, 256, 0, stream>>>(aggb, xb, Wb, Wb + 16384, b1, h1b, h1f8,
                                     nullptr, nullptr, nullptr, nullptr);

  // layer 2 + 3 epilogue fusion (h2 never stored)
  k_agg8<<<(NN + 7) / 8, 256, 0, stream>>>(h1f8, offs, ends, srcs, aggb);
  k_gemm<1><<<NGB, 256, 0, stream>>>(aggb, h1b, Wb + 32768, Wb + 49152, b2,
                                     nullptr, nullptr, W3rel, W3root, y1, P2);

  // final: Σ_e y1[src_e] + Σ P2 -> scalar
  k_esum<<<RED_B, 256, 0, stream>>>(src, y1, P1);
  k_final<<<1, 256, 0, stream>>>(P1, P2, b3, outp);
}

// Round 16
// 190.316 us; speedup vs baseline: 1.3930x; 1.0577x over previous
//
#include <hip/hip_runtime.h>

#define NN 100000
#define NF 128
#define NE 1600000
#define NBK 782   // ceil(NN/128) buckets of 128 dst nodes
#define CH 4096   // edges per binning chunk
#define BINB 391  // (NE+CH-1)/CH bin blocks
#define MAXB 2816 // padded region per bucket (mean 2046, ~17 sigma headroom)
#define RED_B 512 // blocks for esum partial reduction
#define NGB 1563  // (NN+63)/64 gemm blocks
#define CVTX8B 6250  // NN*NF/8/256 blocks for x->fp8 conversion

typedef unsigned short ushort_t;
typedef unsigned char uchar_t;
typedef __attribute__((ext_vector_type(8))) short bf16x8;
typedef __attribute__((ext_vector_type(4))) float f32x4;
typedef __attribute__((ext_vector_type(2))) float f32x2;

__device__ inline ushort_t f2bf(float f) {  // RNE
  union { float f; unsigned u; } v; v.f = f;
  const unsigned r = v.u + 0x7FFFu + ((v.u >> 16) & 1u);
  return (ushort_t)(r >> 16);
}

// 4 packed fp8 e4m3 -> 4 bf16 (RNE both ways; HW cvt)
__device__ inline ushort4 f8x4_bf(unsigned u) {
  const f32x2 a = __builtin_amdgcn_cvt_pk_f32_fp8((int)u, false);
  const f32x2 b = __builtin_amdgcn_cvt_pk_f32_fp8((int)u, true);
  ushort4 r;
  r.x = f2bf(a[0]); r.y = f2bf(a[1]); r.z = f2bf(b[0]); r.w = f2bf(b[1]);
  return r;
}

// ---------------------------------------------- block-wide exclusive scan
__device__ inline void block_scan(const int* hist, int* lofs, int* wsum) {
  const int t = threadIdx.x;
  const int b4 = t * 4;
  const int h0 = hist[b4], h1 = hist[b4 + 1], h2 = hist[b4 + 2], h3 = hist[b4 + 3];
  const int tsum = h0 + h1 + h2 + h3;
  const int lane = t & 63, w = t >> 6;
  int s = tsum;
#pragma unroll
  for (int o = 1; o < 64; o <<= 1) {
    const int u = __shfl_up(s, o);
    if (lane >= o) s += u;
  }
  if (lane == 63) wsum[w] = s;
  __syncthreads();
  int add = 0;
  for (int i = 0; i < w; ++i) add += wsum[i];
  const int ex = add + s - tsum;
  lofs[b4] = ex;
  lofs[b4 + 1] = ex + h0;
  lofs[b4 + 2] = ex + h0 + h1;
  lofs[b4 + 3] = ex + h0 + h1 + h2;
}

// ---------------- merged prep: bin (blocks 0..BINB) || weight cvt || x->fp8
__global__ __launch_bounds__(256) void k_prep(
    const int* __restrict__ src, const int* __restrict__ dst,
    int* __restrict__ bcursor, int* __restrict__ packed,
    const float* __restrict__ x, unsigned* __restrict__ x8u,
    const float* __restrict__ w0, const float* __restrict__ w1,
    const float* __restrict__ w2, const float* __restrict__ w3,
    ushort_t* __restrict__ wout) {
  __shared__ int hist[1024];
  __shared__ int lofs[1024];
  __shared__ int wsum[4];
  __shared__ int gofs[NBK];
  __shared__ int list[CH];
  __shared__ unsigned short blist[CH];
  const int blk = blockIdx.x;
  const int t = threadIdx.x;

  if (blk >= BINB + 64) {  // ---- x -> fp8 (8 floats/thread, streaming)
    const size_t i = (size_t)(blk - BINB - 64) * 256 + t;
    const float4 v0 = *reinterpret_cast<const float4*>(x + i * 8);
    const float4 v1 = *reinterpret_cast<const float4*>(x + i * 8 + 4);
    int lo = __builtin_amdgcn_cvt_pk_fp8_f32(v0.x, v0.y, 0, false);
    lo = __builtin_amdgcn_cvt_pk_fp8_f32(v0.z, v0.w, lo, true);
    int hi = __builtin_amdgcn_cvt_pk_fp8_f32(v1.x, v1.y, 0, false);
    hi = __builtin_amdgcn_cvt_pk_fp8_f32(v1.z, v1.w, hi, true);
    uint2 o; o.x = (unsigned)lo; o.y = (unsigned)hi;
    *reinterpret_cast<uint2*>(x8u + i * 2) = o;
    return;
  }
  if (blk >= BINB) {  // ---- weight conversion (bf16 -- GEMM B operand)
    const int i = (blk - BINB) * 256 + t;
    wout[i] = f2bf(w0[i]);
    wout[16384 + i] = f2bf(w1[i]);
    wout[32768 + i] = f2bf(w2[i]);
    wout[49152 + i] = f2bf(w3[i]);
    return;
  }

  // ---- bin chunk
  const int e0 = blk * CH;
  const int n = min(CH, NE - e0);

  for (int i = t; i < 1024; i += 256) hist[i] = 0;
  __syncthreads();
  for (int i = t; i < n; i += 256) atomicAdd(&hist[dst[e0 + i] >> 7], 1);
  __syncthreads();
  block_scan(hist, lofs, wsum);
  __syncthreads();
  for (int b = t; b < NBK; b += 256) {
    const int cnt = hist[b];
    gofs[b] = cnt ? atomicAdd(&bcursor[b], cnt) : 0;
    hist[b] = 0;
  }
  __syncthreads();
  for (int i = t; i < n; i += 256) {
    const int d = dst[e0 + i];
    const int s = src[e0 + i];
    const int b = d >> 7;
    const int r = atomicAdd(&hist[b], 1);
    const int q = lofs[b] + r;
    list[q] = ((d & 127) << 17) | s;
    blist[q] = (unsigned short)b;
  }
  __syncthreads();
  for (int q = t; q < n; q += 256) {
    const int b = blist[q];
    const int idx = gofs[b] + (q - lofs[b]);
    if (idx < MAXB) packed[b * MAXB + idx] = list[q];
  }
}

// --------------------------------- second-level sort: exact CSR per bucket
__global__ __launch_bounds__(256) void k_sort2(int* __restrict__ packed,
                                               const int* __restrict__ bcursor,
                                               int* __restrict__ offs,
                                               int* __restrict__ ends) {
  __shared__ int plist[MAXB];
  __shared__ int slist[MAXB];
  __shared__ int hist[128];
  __shared__ int lofs[128];
  __shared__ int wsum2[2];
  const int b = blockIdx.x, t = threadIdx.x;
  const int beg = b * MAXB;
  const int n = min(bcursor[b], MAXB);

  for (int i = t; i < n; i += 256) plist[i] = packed[beg + i];
  if (t < 128) hist[t] = 0;
  __syncthreads();
  for (int i = t; i < n; i += 256) atomicAdd(&hist[plist[i] >> 17], 1);
  __syncthreads();
  int s = (t < 128) ? hist[t] : 0;
  {
    const int lane = t & 63;
#pragma unroll
    for (int o = 1; o < 64; o <<= 1) {
      const int u = __shfl_up(s, o);
      if (lane >= o) s += u;
    }
    if (t < 128 && lane == 63) wsum2[t >> 6] = s;
  }
  __syncthreads();
  if (t < 128) {
    const int ex = s - hist[t] + ((t >= 64) ? wsum2[0] : 0);
    lofs[t] = ex;
    const int node = (b << 7) + t;
    if (node < NN) {
      offs[node] = beg + ex;
      ends[node] = beg + ex + hist[t];
    }
    hist[t] = 0;
  }
  __syncthreads();
  for (int i = t; i < n; i += 256) {
    const int p = plist[i];
    const int ld = p >> 17;
    const int r = atomicAdd(&hist[ld], 1);
    slist[lofs[ld] + r] = p & 0x1FFFF;
  }
  __syncthreads();
  for (int i = t; i < n; i += 256) packed[beg + i] = slist[i];
}

// ------------------------------------- gather aggregation (fp8 in, fp8 out)
// Line-request-bound (~105 G lines/s); fp8 rows = 2 lines/edge.
// 2 nodes per wave: half-wave (32 lanes) per node, uint (4 fp8)/lane.
// Accumulate fp32; output fp8 (RNE, unbiased; sums sigma~4 << 448 range).
__global__ __launch_bounds__(256) void k_agg8(const uchar_t* __restrict__ f8,
                                              const int* __restrict__ offs,
                                              const int* __restrict__ ends,
                                              const int* __restrict__ srcs,
                                              uchar_t* __restrict__ out8) {
  const int lane = threadIdx.x & 63;
  const int wid = threadIdx.x >> 6;
  const int node = blockIdx.x * 8 + wid * 2 + (lane >> 5);
  if (node >= NN) return;
  const int c = (lane & 31) * 4;  // byte/feature offset (4 feats per lane)
  const int beg = offs[node];
  const int end = ends[node];

  float x0 = 0.f, y0 = 0.f, z0 = 0.f, w0 = 0.f;
  float x1 = 0.f, y1 = 0.f, z1 = 0.f, w1 = 0.f;
  float x2 = 0.f, y2 = 0.f, z2 = 0.f, w2 = 0.f;
  float x3 = 0.f, y3 = 0.f, z3 = 0.f, w3 = 0.f;
  float x4 = 0.f, y4 = 0.f, z4 = 0.f, w4 = 0.f;
  float x5 = 0.f, y5 = 0.f, z5 = 0.f, w5 = 0.f;
  float x6 = 0.f, y6 = 0.f, z6 = 0.f, w6 = 0.f;
  float x7 = 0.f, y7 = 0.f, z7 = 0.f, w7 = 0.f;

  int e = beg;
  for (; e + 8 <= end; e += 8) {
    const int s0 = srcs[e], s1 = srcs[e + 1], s2 = srcs[e + 2], s3 = srcs[e + 3];
    const int s4 = srcs[e + 4], s5 = srcs[e + 5], s6 = srcs[e + 6], s7 = srcs[e + 7];
    const unsigned u0 = *(const unsigned*)(f8 + s0 * NF + c);
    const unsigned u1 = *(const unsigned*)(f8 + s1 * NF + c);
    const unsigned u2 = *(const unsigned*)(f8 + s2 * NF + c);
    const unsigned u3 = *(const unsigned*)(f8 + s3 * NF + c);
    const unsigned u4 = *(const unsigned*)(f8 + s4 * NF + c);
    const unsigned u5 = *(const unsigned*)(f8 + s5 * NF + c);
    const unsigned u6 = *(const unsigned*)(f8 + s6 * NF + c);
    const unsigned u7 = *(const unsigned*)(f8 + s7 * NF + c);
    {
      const f32x2 a = __builtin_amdgcn_cvt_pk_f32_fp8((int)u0, false);
      const f32x2 b = __builtin_amdgcn_cvt_pk_f32_fp8((int)u0, true);
      x0 += a[0]; y0 += a[1]; z0 += b[0]; w0 += b[1];
    }
    {
      const f32x2 a = __builtin_amdgcn_cvt_pk_f32_fp8((int)u1, false);
      const f32x2 b = __builtin_amdgcn_cvt_pk_f32_fp8((int)u1, true);
      x1 += a[0]; y1 += a[1]; z1 += b[0]; w1 += b[1];
    }
    {
      const f32x2 a = __builtin_amdgcn_cvt_pk_f32_fp8((int)u2, false);
      const f32x2 b = __builtin_amdgcn_cvt_pk_f32_fp8((int)u2, true);
      x2 += a[0]; y2 += a[1]; z2 += b[0]; w2 += b[1];
    }
    {
      const f32x2 a = __builtin_amdgcn_cvt_pk_f32_fp8((int)u3, false);
      const f32x2 b = __builtin_amdgcn_cvt_pk_f32_fp8((int)u3, true);
      x3 += a[0]; y3 += a[1]; z3 += b[0]; w3 += b[1];
    }
    {
      const f32x2 a = __builtin_amdgcn_cvt_pk_f32_fp8((int)u4, false);
      const f32x2 b = __builtin_amdgcn_cvt_pk_f32_fp8((int)u4, true);
      x4 += a[0]; y4 += a[1]; z4 += b[0]; w4 += b[1];
    }
    {
      const f32x2 a = __builtin_amdgcn_cvt_pk_f32_fp8((int)u5, false);
      const f32x2 b = __builtin_amdgcn_cvt_pk_f32_fp8((int)u5, true);
      x5 += a[0]; y5 += a[1]; z5 += b[0]; w5 += b[1];
    }
    {
      const f32x2 a = __builtin_amdgcn_cvt_pk_f32_fp8((int)u6, false);
      const f32x2 b = __builtin_amdgcn_cvt_pk_f32_fp8((int)u6, true);
      x6 += a[0]; y6 += a[1]; z6 += b[0]; w6 += b[1];
    }
    {
      const f32x2 a = __builtin_amdgcn_cvt_pk_f32_fp8((int)u7, false);
      const f32x2 b = __builtin_amdgcn_cvt_pk_f32_fp8((int)u7, true);
      x7 += a[0]; y7 += a[1]; z7 += b[0]; w7 += b[1];
    }
  }
  for (; e + 2 <= end; e += 2) {
    const int s0 = srcs[e], s1 = srcs[e + 1];
    const unsigned u0 = *(const unsigned*)(f8 + s0 * NF + c);
    const unsigned u1 = *(const unsigned*)(f8 + s1 * NF + c);
    {
      const f32x2 a = __builtin_amdgcn_cvt_pk_f32_fp8((int)u0, false);
      const f32x2 b = __builtin_amdgcn_cvt_pk_f32_fp8((int)u0, true);
      x0 += a[0]; y0 += a[1]; z0 += b[0]; w0 += b[1];
    }
    {
      const f32x2 a = __builtin_amdgcn_cvt_pk_f32_fp8((int)u1, false);
      const f32x2 b = __builtin_amdgcn_cvt_pk_f32_fp8((int)u1, true);
      x1 += a[0]; y1 += a[1]; z1 += b[0]; w1 += b[1];
    }
  }
  for (; e < end; ++e) {
    const unsigned u = *(const unsigned*)(f8 + srcs[e] * NF + c);
    const f32x2 a = __builtin_amdgcn_cvt_pk_f32_fp8((int)u, false);
    const f32x2 b = __builtin_amdgcn_cvt_pk_f32_fp8((int)u, true);
    x0 += a[0]; y0 += a[1]; z0 += b[0]; w0 += b[1];
  }
  const float X = ((x0 + x1) + (x2 + x3)) + ((x4 + x5) + (x6 + x7));
  const float Y = ((y0 + y1) + (y2 + y3)) + ((y4 + y5) + (y6 + y7));
  const float Z = ((z0 + z1) + (z2 + z3)) + ((z4 + z5) + (z6 + z7));
  const float W = ((w0 + w1) + (w2 + w3)) + ((w4 + w5) + (w6 + w7));
  int o = __builtin_amdgcn_cvt_pk_fp8_f32(X, Y, 0, false);
  o = __builtin_amdgcn_cvt_pk_fp8_f32(Z, W, o, true);
  *(unsigned*)(out8 + node * NF + c) = (unsigned)o;  // coalesced uint store
}

// ------------------------------------------------------------- MFMA GEMM
// A operands stored fp8; staging converts fp8->bf16 into LDS (VALU is idle).
// B operands bf16, fp32 accumulate -- MFMA path unchanged.
// MODE 0: write relu(v) as fp8 to out8 (layer-2 feature table). In-place
//         over A2 is safe: block reads its rows to LDS before epilogue.
// MODE 1: layer 2+3 fused epilogue via shfl_xor j-reduction:
//         y1[node] = h2.W3rel, P2[block] = sum_nodes h2.W3root.
template <int MODE>
__global__ __launch_bounds__(256) void k_gemm(const uchar_t* __restrict__ A1,
                                              const uchar_t* __restrict__ A2,
                                              const ushort_t* __restrict__ B1,
                                              const ushort_t* __restrict__ B2,
                                              const float* __restrict__ bias,
                                              uchar_t* __restrict__ out8,
                                              const float* __restrict__ W3rel,
                                              const float* __restrict__ W3root,
                                              float* __restrict__ y1,
                                              float* __restrict__ P2) {
  __shared__ ushort_t As[64][264];  // +8 pad: 2-way LDS conflict only
  __shared__ float y1s[4][64];
  __shared__ float y2s[4][64];
  const int tid = threadIdx.x;
  const int lane = tid & 63;
  const int wid = tid >> 6;
  const int bm = blockIdx.x * 64;

  const int jb = wid * 32 + (lane & 15);
  const int kc = (lane >> 4) * 8;
  bf16x8 bfrag[2][8];
#pragma unroll
  for (int nt = 0; nt < 2; ++nt) {
    const int j = jb + nt * 16;
#pragma unroll
    for (int ks = 0; ks < 4; ++ks) {
      bfrag[nt][ks] = *reinterpret_cast<const bf16x8*>(B1 + j * 128 + ks * 32 + kc);
      bfrag[nt][ks + 4] = *reinterpret_cast<const bf16x8*>(B2 + j * 128 + ks * 32 + kc);
    }
  }

  // stage A: fp8 rows -> bf16 LDS tile (32 fp8 = 2 uint4 per thread/source)
  {
    const int r = tid >> 2, p = tid & 3;
    const int node = bm + r;
#pragma unroll
    for (int s = 0; s < 2; ++s) {
      const uchar_t* __restrict__ sp = s ? A2 : A1;
      uint4 q0 = make_uint4(0u, 0u, 0u, 0u), q1 = q0;  // fp8 0x00 == +0.0
      if (node < NN) {
        q0 = *reinterpret_cast<const uint4*>(sp + (size_t)node * 128 + p * 32);
        q1 = *reinterpret_cast<const uint4*>(sp + (size_t)node * 128 + p * 32 + 16);
      }
      const int col = s * 128 + p * 32;
      *reinterpret_cast<ushort4*>(&As[r][col + 0]) = f8x4_bf(q0.x);
      *reinterpret_cast<ushort4*>(&As[r][col + 4]) = f8x4_bf(q0.y);
      *reinterpret_cast<ushort4*>(&As[r][col + 8]) = f8x4_bf(q0.z);
      *reinterpret_cast<ushort4*>(&As[r][col + 12]) = f8x4_bf(q0.w);
      *reinterpret_cast<ushort4*>(&As[r][col + 16]) = f8x4_bf(q1.x);
      *reinterpret_cast<ushort4*>(&As[r][col + 20]) = f8x4_bf(q1.y);
      *reinterpret_cast<ushort4*>(&As[r][col + 24]) = f8x4_bf(q1.z);
      *reinterpret_cast<ushort4*>(&As[r][col + 28]) = f8x4_bf(q1.w);
    }
  }
  __syncthreads();

  f32x4 acc[4][2];
#pragma unroll
  for (int mt = 0; mt < 4; ++mt) {
    acc[mt][0] = (f32x4)0.f;
    acc[mt][1] = (f32x4)0.f;
  }

  const int ar = lane & 15;
#pragma unroll
  for (int ks = 0; ks < 8; ++ks) {
#pragma unroll
    for (int mt = 0; mt < 4; ++mt) {
      const bf16x8 a = *reinterpret_cast<const bf16x8*>(&As[mt * 16 + ar][ks * 32 + kc]);
      acc[mt][0] = __builtin_amdgcn_mfma_f32_16x16x32_bf16(a, bfrag[0][ks], acc[mt][0], 0, 0, 0);
      acc[mt][1] = __builtin_amdgcn_mfma_f32_16x16x32_bf16(a, bfrag[1][ks], acc[mt][1], 0, 0, 0);
    }
  }

  // epilogue (C/D: col=lane&15 -> j, row=(lane>>4)*4+reg -> node)
  const int rg = (lane >> 4) * 4;
  if (MODE == 0) {
#pragma unroll
    for (int nt = 0; nt < 2; ++nt) {
      const int j = jb + nt * 16;
      const float bv = bias[j];
#pragma unroll
      for (int mt = 0; mt < 4; ++mt) {
#pragma unroll
        for (int r = 0; r < 4; ++r) {
          const int node = bm + mt * 16 + rg + r;
          if (node < NN) {
            const float v = fmaxf(acc[mt][nt][r] + bv, 0.f);
            const int u8 = __builtin_amdgcn_cvt_pk_fp8_f32(v, v, 0, false);
            out8[(size_t)node * 128 + j] = (uchar_t)(u8 & 0xFF);
          }
        }
      }
    }
  } else {
    const float bv0 = bias[jb], bv1 = bias[jb + 16];
    const float wr0 = W3rel[jb], wr1 = W3rel[jb + 16];
    const float wt0 = W3root[jb], wt1 = W3root[jb + 16];
#pragma unroll
    for (int mt = 0; mt < 4; ++mt) {
#pragma unroll
      for (int r = 0; r < 4; ++r) {
        const float v0 = fmaxf(acc[mt][0][r] + bv0, 0.f);
        const float v1 = fmaxf(acc[mt][1][r] + bv1, 0.f);
        float s1 = v0 * wr0 + v1 * wr1;
        float s2 = v0 * wt0 + v1 * wt1;
#pragma unroll
        for (int o = 1; o < 16; o <<= 1) {
          s1 += __shfl_xor(s1, o);
          s2 += __shfl_xor(s2, o);
        }
        if ((lane & 15) == 0) {
          const int nloc = mt * 16 + rg + r;
          y1s[wid][nloc] = s1;
          y2s[wid][nloc] = s2;
        }
      }
    }
    __syncthreads();
    if (tid < 64) {
      const int node = bm + tid;
      const float s1 = (y1s[0][tid] + y1s[1][tid]) + (y1s[2][tid] + y1s[3][tid]);
      float p = (node < NN)
                    ? (y2s[0][tid] + y2s[1][tid]) + (y2s[2][tid] + y2s[3][tid])
                    : 0.f;
      if (node < NN) y1[node] = s1;
#pragma unroll
      for (int o = 32; o > 0; o >>= 1) p += __shfl_down(p, o);
      if (tid == 0) P2[blockIdx.x] = p;
    }
  }
}

// --------------------------- P1 partials: Σ_e y1[src_e] (L2-resident table)
__global__ __launch_bounds__(256) void k_esum(const int* __restrict__ src,
                                              const float* __restrict__ y1,
                                              float* __restrict__ P1) {
  float p = 0.f;
  const int stride = RED_B * 256;
  for (int e = blockIdx.x * 256 + threadIdx.x; e < NE; e += stride)
    p += y1[src[e]];
#pragma unroll
  for (int o = 32; o > 0; o >>= 1) p += __shfl_down(p, o);
  __shared__ float tmp[4];
  const int lane = threadIdx.x & 63, w = threadIdx.x >> 6;
  if (lane == 0) tmp[w] = p;
  __syncthreads();
  if (threadIdx.x == 0)
    P1[blockIdx.x] = (tmp[0] + tmp[1]) + (tmp[2] + tmp[3]);
}

__global__ __launch_bounds__(256) void k_final(const float* __restrict__ P1,
                                               const float* __restrict__ P2,
                                               const float* __restrict__ b3,
                                               float* __restrict__ out) {
  const int t = threadIdx.x;
  float v = P1[t] + P1[t + 256];
  for (int i = t; i < NGB; i += 256) v += P2[i];
#pragma unroll
  for (int o = 32; o > 0; o >>= 1) v += __shfl_down(v, o);
  __shared__ float tmp[4];
  if ((t & 63) == 0) tmp[t >> 6] = v;
  __syncthreads();
  if (t == 0)
    out[0] = ((tmp[0] + tmp[1]) + (tmp[2] + tmp[3])) * (1.0f / NN) + b3[0];
}

// ---------------------------------------------------------------------------
extern "C" void kernel_launch(void* const* d_in, const int* in_sizes, int n_in,
                              void* d_out, int out_size, void* d_ws, size_t ws_size,
                              hipStream_t stream) {
  const float* x = (const float*)d_in[0];
  const int* ei = (const int*)d_in[1];
  const float* W1rel = (const float*)d_in[2];
  const float* b1 = (const float*)d_in[3];
  const float* W1root = (const float*)d_in[4];
  const float* W2rel = (const float*)d_in[5];
  const float* b2 = (const float*)d_in[6];
  const float* W2root = (const float*)d_in[7];
  const float* W3rel = (const float*)d_in[8];
  const float* b3 = (const float*)d_in[9];
  const float* W3root = (const float*)d_in[10];

  const int* src = ei;       // edge_index[0]
  const int* dst = ei + NE;  // edge_index[1]

  char* ws = (char*)d_ws;
  size_t off = 0;
  uchar_t* x8    = (uchar_t*)(ws + off);  off += (size_t)NN * NF;      // 12.8 MB
  uchar_t* agg8  = (uchar_t*)(ws + off);  off += (size_t)NN * NF;      // 12.8 MB
  ushort_t* Wb   = (ushort_t*)(ws + off); off += 65536 * 2;            // 128 KB
  int* offs    = (int*)(ws + off); off += (size_t)NN * 4;              // 400 KB
  int* ends    = (int*)(ws + off); off += (size_t)NN * 4;              // 400 KB
  float* y1    = (float*)(ws + off); off += (size_t)NN * 4;            // 400 KB
  int* bcursor = (int*)(ws + off); off += 1024 * 4;
  float* P1    = (float*)(ws + off); off += RED_B * 4;
  float* P2    = (float*)(ws + off); off += 2048 * 4;
  int* packed  = (int*)(ws + off); off += (size_t)NBK * MAXB * 4;      // 8.8 MB
  int* srcs    = packed;     // k_sort2 rewrites packed in place
  uchar_t* h1f8 = x8;        // gemm<0> overwrites x8 in place (block-safe)
  float* outp = (float*)d_out;

  hipMemsetAsync(bcursor, 0, 1024 * sizeof(int), stream);

  // merged prep: bin || weight-cvt || x->fp8 (concurrent in one dispatch)
  k_prep<<<BINB + 64 + CVTX8B, 256, 0, stream>>>(src, dst, bcursor, packed,
                                                 x, (unsigned*)x8,
                                                 W1rel, W1root, W2rel, W2root, Wb);
  k_sort2<<<NBK, 256, 0, stream>>>(packed, bcursor, offs, ends);

  // layer 1: fp8 gather -> fp8 agg; gemm (fp8 A operands, bf16 MFMA);
  // h1 written fp8 in place over x8
  k_agg8<<<(NN + 7) / 8, 256, 0, stream>>>(x8, offs, ends, srcs, agg8);
  k_gemm<0><<<NGB, 256, 0, stream>>>(agg8, x8, Wb, Wb + 16384, b1, h1f8,
                                     nullptr, nullptr, nullptr, nullptr);

  // layer 2 + 3 epilogue fusion (h2 never stored)
  k_agg8<<<(NN + 7) / 8, 256, 0, stream>>>(h1f8, offs, ends, srcs, agg8);
  k_gemm<1><<<NGB, 256, 0, stream>>>(agg8, h1f8, Wb + 32768, Wb + 49152, b2,
                                     nullptr, W3rel, W3root, y1, P2);

  // final: Σ_e y1[src_e] + Σ P2 -> scalar
  k_esum<<<RED_B, 256, 0, stream>>>(src, y1, P1);
  k_final<<<1, 256, 0, stream>>>(P1, P2, b3, outp);
}